// Round 11
// baseline (466.426 us; speedup 1.0000x reference)
//
#include <hip/hip_runtime.h>

#define NTOP 256

typedef __attribute__((ext_vector_type(8))) short bf16x8;
typedef __attribute__((ext_vector_type(4))) float f32x4;

// round-to-nearest-even split of fp32 into bf16 hi/lo, packed (hi<<16)|lo
__device__ inline unsigned int packbf(float x) {
  unsigned int u = __float_as_uint(x);
  unsigned int r = (u + 0x7fffu + ((u >> 16) & 1u)) & 0xffff0000u;
  float res = x - __uint_as_float(r);
  unsigned int u2 = __float_as_uint(res);
  unsigned int r2 = u2 + 0x7fffu + ((u2 >> 16) & 1u);
  return r | (r2 >> 16);
}

__device__ inline float tanh_fast(float x) {
  float e = __expf(2.f * x);
  return 1.f - 2.f / (e + 1.f);
}

// ---------------------------------------------------------------- K1
// MFMA recurrence. 1024 thr = 16 waves; wave w owns outputs
// j in [16w,16w+16). Wc^T stays in 64 regs of bf16 hi/lo B-fragments
// (loaded once; fp32 sum Wih+Whh then exact RNE split). h broadcast via
// two 512-B LDS planes (hi/lo), double-buffered. Per step: 16 broadcast
// ds_read_b128 + 32 MFMA (bf16x4: hh+hl+lh+ll) + tanh + 1 barrier.
// A-rows are identical (h broadcast) so acc[0] of ANY lane = dot for its
// j — no cross-lane reduce. H rows collect in a 32-row LDS ring, dumped
// to global every 32 steps (no vmem in flight at per-step barriers).
__global__ __launch_bounds__(1024)
__attribute__((amdgpu_waves_per_eu(4, 4)))
void rsbc_recur(
    const float* __restrict__ Wih, const float* __restrict__ Whh,
    const float* __restrict__ bih, const float* __restrict__ bhh,
    const float* __restrict__ h0, unsigned int* __restrict__ Hpack) {
  __shared__ ushort hh[2][NTOP];          // h hi-plane, double-buffered
  __shared__ ushort hl[2][NTOP];          // h lo-plane
  __shared__ unsigned int hist[32][NTOP]; // H-row ring (packed hi|lo)
  const int tid = threadIdx.x;
  const int w = tid >> 6, l = tid & 63;
  const int l15 = l & 15, g = l >> 4;
  const int j = 16 * w + l15;             // this lane's output index
  const float bj = bih[j] + bhh[j];

  // h0 -> planes buf0
  if (tid < NTOP) {
    unsigned int u = packbf(h0[tid]);
    hh[0][tid] = (ushort)(u >> 16);
    hl[0][tid] = (ushort)(u & 0xffffu);
  }

  // B-fragments: lane holds B[k][j] for k = 32t + 8g + e (e=0..7).
  // First pass: W_ih only (step 0).
  bf16x8 bh[8], bl[8];
#pragma unroll
  for (int t = 0; t < 8; ++t) {
    const float* src = Wih + j * NTOP + 32 * t + 8 * g;
    float4 u0 = *reinterpret_cast<const float4*>(src);
    float4 u1 = *reinterpret_cast<const float4*>(src + 4);
    float f[8] = {u0.x, u0.y, u0.z, u0.w, u1.x, u1.y, u1.z, u1.w};
#pragma unroll
    for (int e = 0; e < 8; ++e) {
      unsigned int p = packbf(f[e]);
      bh[t][e] = (short)(p >> 16);
      bl[t][e] = (short)(p & 0xffffu);
    }
  }
  __syncthreads();

  // one recurrence step: read buf rb, write buf wb, emit H row r
  auto step = [&](int rb, int wb, int r) {
    const ushort* Hh = hh[rb];
    const ushort* Hl = hl[rb];
    f32x4 acc0 = {0.f, 0.f, 0.f, 0.f}, acc1 = {0.f, 0.f, 0.f, 0.f};
#pragma unroll
    for (int t = 0; t < 8; t += 2) {
      bf16x8 a0h = *reinterpret_cast<const bf16x8*>(Hh + 32 * t + 8 * g);
      bf16x8 a0l = *reinterpret_cast<const bf16x8*>(Hl + 32 * t + 8 * g);
      acc0 = __builtin_amdgcn_mfma_f32_16x16x32_bf16(a0h, bh[t], acc0, 0, 0, 0);
      acc0 = __builtin_amdgcn_mfma_f32_16x16x32_bf16(a0h, bl[t], acc0, 0, 0, 0);
      acc0 = __builtin_amdgcn_mfma_f32_16x16x32_bf16(a0l, bh[t], acc0, 0, 0, 0);
      acc0 = __builtin_amdgcn_mfma_f32_16x16x32_bf16(a0l, bl[t], acc0, 0, 0, 0);
      bf16x8 a1h = *reinterpret_cast<const bf16x8*>(Hh + 32 * (t + 1) + 8 * g);
      bf16x8 a1l = *reinterpret_cast<const bf16x8*>(Hl + 32 * (t + 1) + 8 * g);
      acc1 = __builtin_amdgcn_mfma_f32_16x16x32_bf16(a1h, bh[t + 1], acc1, 0, 0, 0);
      acc1 = __builtin_amdgcn_mfma_f32_16x16x32_bf16(a1h, bl[t + 1], acc1, 0, 0, 0);
      acc1 = __builtin_amdgcn_mfma_f32_16x16x32_bf16(a1l, bh[t + 1], acc1, 0, 0, 0);
      acc1 = __builtin_amdgcn_mfma_f32_16x16x32_bf16(a1l, bl[t + 1], acc1, 0, 0, 0);
    }
    float d = acc0[0] + acc1[0];          // every lane: dot for its j
    float v = tanh_fast(d + bj);
    unsigned int u = packbf(v);
    if (g == 0) {                         // one lane-group writes
      hh[wb][j] = (ushort)(u >> 16);
      hl[wb][j] = (ushort)(u & 0xffffu);
      hist[r & 31][j] = u;
    }
    __syncthreads();
  };

  // step 0 with B = W_ih
  step(0, 1, 0);

  // rebuild B-fragments as Wc = W_ih + W_hh (exact fp32 sum, then split)
#pragma unroll
  for (int t = 0; t < 8; ++t) {
    const float* s1 = Wih + j * NTOP + 32 * t + 8 * g;
    const float* s2 = Whh + j * NTOP + 32 * t + 8 * g;
    float4 a0 = *reinterpret_cast<const float4*>(s1);
    float4 a1 = *reinterpret_cast<const float4*>(s1 + 4);
    float4 c0 = *reinterpret_cast<const float4*>(s2);
    float4 c1 = *reinterpret_cast<const float4*>(s2 + 4);
    float f[8] = {a0.x + c0.x, a0.y + c0.y, a0.z + c0.z, a0.w + c0.w,
                  a1.x + c1.x, a1.y + c1.y, a1.z + c1.z, a1.w + c1.w};
#pragma unroll
    for (int e = 0; e < 8; ++e) {
      unsigned int p = packbf(f[e]);
      bh[t][e] = (short)(p >> 16);
      bl[t][e] = (short)(p & 0xffffu);
    }
  }

#pragma unroll 1
  for (int r = 1; r < 255; ++r) {
    step(r & 1, (r + 1) & 1, r);
    if ((r & 31) == 31) {                 // dump rows r-31..r
      const int r0 = r - 31;
#pragma unroll
      for (int it = 0; it < 8; ++it) {
        int idx = tid + 1024 * it;        // 0..8191
        int sr = idx >> 8, jj = idx & 255;
        Hpack[(r0 + sr) * NTOP + jj] = hist[sr][jj];
      }
      __syncthreads();                    // ring WAR protection
    }
  }
  // tail: rows 224..254 (31 rows, slots 0..30)
#pragma unroll
  for (int it = 0; it < 8; ++it) {
    int idx = tid + 1024 * it;
    int sr = idx >> 8, jj = idx & 255;
    if (sr < 31) Hpack[(224 + sr) * NTOP + jj] = hist[sr][jj];
  }
}

// ---------------------------------------------------------------- K2
// R8's proven K2 (119 us): bf16x3 MFMA GEMM (Z @ H^T) + sigmoid +
// stick-breaking, 512 thr (8 waves 2x4), BM=128, N=256, K in 4 chunks
// of 64, 144-B LDS row stride, loads-before-barrier pipelining, LDS eta
// epilogue with 4-thread/row segmented cumprod, full-line float4 stores.
// waves_per_eu(2,2): LDS caps at 1 block/CU anyway; 256-reg budget.
__global__ __launch_bounds__(512)
__attribute__((amdgpu_waves_per_eu(2, 2)))
void rsbc_gemm_sb(
    const float* __restrict__ z, const unsigned int* __restrict__ Hpack,
    float* __restrict__ out) {
  constexpr int AS = 72;   // A row stride (bf16 elems), 144 B
  constexpr int BS = 72;   // B row stride
  constexpr int ES = 260;  // eta row stride (floats)
  __shared__ __align__(16) char smem[135168];
  __shared__ float logtab[256];
  ushort* Ahi = reinterpret_cast<ushort*>(smem);
  ushort* Alo = Ahi + 128 * AS;
  ushort* Bhi = Alo + 128 * AS;
  ushort* Blo = Bhi + 256 * BS;
  float* eta = reinterpret_cast<float*>(smem);
  float* segT = eta + 128 * ES;

  const int tid = threadIdx.x;
  const size_t row0 = (size_t)blockIdx.x * 128;
  const int wid = tid >> 6, lane = tid & 63;
  const int wr = wid >> 2, wc = wid & 3;
  const int l15 = lane & 15, l4 = lane >> 4;

  if (tid < 255) logtab[tid] = logf((float)(255 - tid));

  f32x4 acc[4][4];
#pragma unroll
  for (int mt = 0; mt < 4; ++mt)
#pragma unroll
    for (int nt = 0; nt < 4; ++nt) acc[mt][nt] = (f32x4){0.f, 0.f, 0.f, 0.f};

  for (int kc = 0; kc < 4; ++kc) {
    const int kb = kc * 64;
    float4 zreg[4];
#pragma unroll
    for (int it = 0; it < 4; ++it) {
      int idx = tid + 512 * it;        // 0..2047
      int r = idx >> 4, q = idx & 15;  // r 0..127
      zreg[it] = *reinterpret_cast<const float4*>(
          z + (row0 + r) * NTOP + kb + 4 * q);
    }
    uint4 hreg[8];
#pragma unroll
    for (int it = 0; it < 8; ++it) {
      int idx = tid + 512 * it;        // 0..4095
      int r = idx >> 4, q = idx & 15;  // r 0..255
      hreg[it] = (r < 255)
                     ? *reinterpret_cast<const uint4*>(
                           Hpack + r * NTOP + kb + 4 * q)
                     : make_uint4(0u, 0u, 0u, 0u);
    }
    __syncthreads();                   // previous chunk's frag reads done
#pragma unroll
    for (int it = 0; it < 4; ++it) {
      int idx = tid + 512 * it;
      int r = idx >> 4, q = idx & 15;
      float4 v = zreg[it];
      unsigned int p0 = packbf(v.x), p1 = packbf(v.y),
                   p2 = packbf(v.z), p3 = packbf(v.w);
      *reinterpret_cast<ushort4*>(&Ahi[r * AS + 4 * q]) = make_ushort4(
          (ushort)(p0 >> 16), (ushort)(p1 >> 16),
          (ushort)(p2 >> 16), (ushort)(p3 >> 16));
      *reinterpret_cast<ushort4*>(&Alo[r * AS + 4 * q]) = make_ushort4(
          (ushort)(p0 & 0xffff), (ushort)(p1 & 0xffff),
          (ushort)(p2 & 0xffff), (ushort)(p3 & 0xffff));
    }
#pragma unroll
    for (int it = 0; it < 8; ++it) {
      int idx = tid + 512 * it;
      int r = idx >> 4, q = idx & 15;
      uint4 hv = hreg[it];
      *reinterpret_cast<ushort4*>(&Bhi[r * BS + 4 * q]) = make_ushort4(
          (ushort)(hv.x >> 16), (ushort)(hv.y >> 16),
          (ushort)(hv.z >> 16), (ushort)(hv.w >> 16));
      *reinterpret_cast<ushort4*>(&Blo[r * BS + 4 * q]) = make_ushort4(
          (ushort)(hv.x & 0xffff), (ushort)(hv.y & 0xffff),
          (ushort)(hv.z & 0xffff), (ushort)(hv.w & 0xffff));
    }
    __syncthreads();                   // staging visible
#pragma unroll
    for (int ks = 0; ks < 2; ++ks) {
      const int ko = ks * 32 + l4 * 8;
      bf16x8 afh[4], afl[4], bfh[4], bfl[4];
#pragma unroll
      for (int mt = 0; mt < 4; ++mt) {
        int r = 64 * wr + 16 * mt + l15;
        afh[mt] = *reinterpret_cast<const bf16x8*>(&Ahi[r * AS + ko]);
        afl[mt] = *reinterpret_cast<const bf16x8*>(&Alo[r * AS + ko]);
      }
#pragma unroll
      for (int nt = 0; nt < 4; ++nt) {
        int n = 64 * wc + 16 * nt + l15;
        bfh[nt] = *reinterpret_cast<const bf16x8*>(&Bhi[n * BS + ko]);
        bfl[nt] = *reinterpret_cast<const bf16x8*>(&Blo[n * BS + ko]);
      }
#pragma unroll
      for (int mt = 0; mt < 4; ++mt)
#pragma unroll
        for (int nt = 0; nt < 4; ++nt) {
          acc[mt][nt] = __builtin_amdgcn_mfma_f32_16x16x32_bf16(
              afh[mt], bfh[nt], acc[mt][nt], 0, 0, 0);
          acc[mt][nt] = __builtin_amdgcn_mfma_f32_16x16x32_bf16(
              afh[mt], bfl[nt], acc[mt][nt], 0, 0, 0);
          acc[mt][nt] = __builtin_amdgcn_mfma_f32_16x16x32_bf16(
              afl[mt], bfh[nt], acc[mt][nt], 0, 0, 0);
        }
    }
  }
  __syncthreads();                     // frag reads done; smem becomes eta

  // eta = sigmoid(logits) -> LDS   (C/D: col=lane&15, row=(lane>>4)*4+i)
#pragma unroll
  for (int mt = 0; mt < 4; ++mt) {
    int rbase = 64 * wr + 16 * mt + 4 * l4;
#pragma unroll
    for (int nt = 0; nt < 4; ++nt) {
      int c = 64 * wc + 16 * nt + l15;
#pragma unroll
      for (int i = 0; i < 4; ++i) {
        float x = acc[mt][nt][i];
        eta[(rbase + i) * ES + c] = 1.f / (1.f + __expf(-x));
      }
    }
  }
  __syncthreads();

  // stick-breaking: 4 threads per row, segmented cumprod
  const int r = tid >> 2, qk = tid & 3;
  const int kbeg = 64 * qk, kend = (qk == 3) ? 255 : 64 * qk + 64;
  float* er = &eta[r * ES];
  {
    float cp = 1.f;
#pragma unroll 4
    for (int k = kbeg; k < kend; ++k) {
      float x = er[k] - logtab[k];
      float zc = 1.f / (1.f + __expf(-x));
      zc = fminf(fmaxf(zc, 1.1754943508222875e-38f), 0.99999988079071045f);
      er[k] = zc * cp;
      cp *= 1.f - zc;
    }
    segT[r * 4 + qk] = cp;
  }
  __syncthreads();
  {
    float p = 1.f;
    if (qk > 0) p *= segT[r * 4 + 0];
    if (qk > 1) p *= segT[r * 4 + 1];
    if (qk > 2) p *= segT[r * 4 + 2];
    if (qk > 0) {
#pragma unroll 4
      for (int k = kbeg; k < kend; ++k) er[k] *= p;
    }
    if (qk == 3) er[255] = p * segT[r * 4 + 3];
  }
  __syncthreads();

  // coalesced store: 128 rows x 64 float4
#pragma unroll
  for (int it = 0; it < 16; ++it) {
    int idx = tid + 512 * it;          // 0..8191
    int rr = idx >> 6, cq = idx & 63;
    float4 vv = *reinterpret_cast<const float4*>(&eta[rr * ES + 4 * cq]);
    *reinterpret_cast<float4*>(&out[(row0 + rr) * NTOP + 4 * cq]) = vv;
  }
}

// ---------------------------------------------------------------- launch
extern "C" void kernel_launch(void* const* d_in, const int* in_sizes, int n_in,
                              void* d_out, int out_size, void* d_ws, size_t ws_size,
                              hipStream_t stream) {
  const float* z   = (const float*)d_in[0];
  const float* h0  = (const float*)d_in[1];
  const float* Wih = (const float*)d_in[2];
  const float* Whh = (const float*)d_in[3];
  const float* bih = (const float*)d_in[4];
  const float* bhh = (const float*)d_in[5];
  float* out = (float*)d_out;
  unsigned int* Hpack = (unsigned int*)d_ws;  // 255*256 uint32

  rsbc_recur<<<1, 1024, 0, stream>>>(Wih, Whh, bih, bhh, h0, Hpack);
  const int nrows = out_size / NTOP;          // 131072
  const int blocks = nrows / 128;             // 1024
  rsbc_gemm_sb<<<blocks, 512, 0, stream>>>(z, Hpack, out);
}